// Round 1
// baseline (653.326 us; speedup 1.0000x reference)
//
#include <hip/hip_runtime.h>
#include <hip/hip_bf16.h>

// Problem dims (fixed)
#define B_   128
#define S_   25
#define E_   512
#define F_   512
#define H_   512
#define V_   10000
#define KCAT 1536        // F+E+H
#define M_   3200        // B*S
#define NPAD 10112       // 79*128 (padded V)
#define SV   250000      // S*V

typedef __attribute__((ext_vector_type(8))) short bf16x8;   // 8 bf16 in 4 VGPRs
typedef __attribute__((ext_vector_type(4))) float f32x4;

__device__ inline unsigned short f2bf(float f) {
  __hip_bfloat16 h = __float2bfloat16(f);
  return *reinterpret_cast<unsigned short*>(&h);
}

// ---------------------------------------------------------------------------
// Transpose-convert: in f32 [K][N] row-major  ->  out bf16 [Npad][K] (k-major)
// Rows n >= N are zero-filled (padding for the GEMM N-tiles).
// ---------------------------------------------------------------------------
__global__ __launch_bounds__(256) void transpose_to_bf16(
    const float* __restrict__ in, __hip_bfloat16* __restrict__ out,
    int K, int N, int Npad)
{
  __shared__ float tile[32][33];
  int n0 = blockIdx.x * 32, k0 = blockIdx.y * 32;
  int tx = threadIdx.x & 31, ty = threadIdx.x >> 5;   // 32 x 8
  #pragma unroll
  for (int i = 0; i < 32; i += 8) {
    int k = k0 + ty + i, n = n0 + tx;
    tile[ty + i][tx] = (n < N) ? in[(size_t)k * N + n] : 0.0f;
  }
  __syncthreads();
  #pragma unroll
  for (int i = 0; i < 32; i += 8) {
    int n = n0 + ty + i, k = k0 + tx;
    out[(size_t)n * K + k] = __float2bfloat16(tile[tx][ty + i]);
  }
}

// ---------------------------------------------------------------------------
// Build A1[r=t*128+b][0:512]=bf16(base[b]), [512:1024]=bf16(emb[tok(b,t)]).
// Also: init sbf[0] from initial_hidden_state, zero the sync counter.
// ---------------------------------------------------------------------------
__global__ __launch_bounds__(256) void build_a1(
    const int* __restrict__ xT, const float* __restrict__ base,
    const float* __restrict__ init, const float* __restrict__ emb,
    unsigned short* __restrict__ A1, __hip_bfloat16* __restrict__ sbf0,
    unsigned* __restrict__ cnt)
{
  int r = blockIdx.x; int t = r >> 7, b = r & 127;
  int tid = threadIdx.x;
  if (r == 0 && tid == 0) *cnt = 0;
  int tok = xT[b * S_ + t];
  const float* src = (tid < 128) ? (base + (size_t)b * 512 + tid * 4)
                                 : (emb + (size_t)tok * 512 + (tid - 128) * 4);
  float4 v = *(const float4*)src;
  ushort4 o;
  o.x = f2bf(v.x); o.y = f2bf(v.y); o.z = f2bf(v.z); o.w = f2bf(v.w);
  *(ushort4*)(A1 + (size_t)r * 1024 + tid * 4) = o;
  if (r < 128) {
    float2 w = *(const float2*)(init + (size_t)r * 512 + tid * 2);
    sbf0[(size_t)r * 512 + tid * 2]     = __float2bfloat16(w.x);
    sbf0[(size_t)r * 512 + tid * 2 + 1] = __float2bfloat16(w.y);
  }
}

// ---------------------------------------------------------------------------
// GEMM  C = A[M][lda] @ Bt[N][ldb]^T + bias  (both operands bf16 k-major)
// 128x128 tile, BK=64, 4 waves (2x2), each wave 64x64 via 4x4 16x16x32 MFMA.
// LDS tiles XOR-chunk-swizzled (c ^= row&7) -> ~conflict-free ds_read_b128.
// MODE 0: C[r*ldc + n] = v + bias[n]          (pre-activation buffer)
// MODE 1: logits scatter C[b*SV + t*V + n] (n < V only), r = t*128+b
// ---------------------------------------------------------------------------
template<int MODE>
__global__ __launch_bounds__(256) void gemm_bt(
    const __hip_bfloat16* __restrict__ A,
    const __hip_bfloat16* __restrict__ Bt,
    const float* __restrict__ bias,
    float* __restrict__ C,
    int K, int lda, int ldb, int ldc)
{
  __shared__ short As[128 * 64];
  __shared__ short Bs[128 * 64];
  const int tid = threadIdx.x;
  const int w = tid >> 6, l = tid & 63;
  const int tm = blockIdx.y, tn = blockIdx.x;
  const int wm = w >> 1, wn = w & 1;

  f32x4 acc[4][4] = {};

  const int nKT = K >> 6;
  for (int kt = 0; kt < nKT; ++kt) {
    const int k0 = kt << 6;
    uint4 ra[4], rb[4];
    #pragma unroll
    for (int p = 0; p < 4; ++p) {
      int idx = p * 256 + tid;
      int row = idx >> 3;
      int cs  = idx & 7;   // linear global chunk (8 bf16 = 16B)
      ra[p] = *(const uint4*)((const char*)(A  + (size_t)(tm * 128 + row) * lda + k0) + cs * 16);
      rb[p] = *(const uint4*)((const char*)(Bt + (size_t)(tn * 128 + row) * ldb + k0) + cs * 16);
    }
    __syncthreads();   // all waves done reading LDS from previous iter
    #pragma unroll
    for (int p = 0; p < 4; ++p) {
      int idx = p * 256 + tid;
      int row = idx >> 3;
      int cd  = (idx & 7) ^ (row & 7);   // swizzled LDS chunk
      *(uint4*)((char*)As + row * 128 + cd * 16) = ra[p];
      *(uint4*)((char*)Bs + row * 128 + cd * 16) = rb[p];
    }
    __syncthreads();
    #pragma unroll
    for (int kk = 0; kk < 2; ++kk) {
      bf16x8 af[4], bfr[4];
      #pragma unroll
      for (int m = 0; m < 4; ++m) {
        int row = wm * 64 + m * 16 + (l & 15);
        int c   = (kk * 4 + (l >> 4)) ^ (row & 7);
        af[m] = *(const bf16x8*)((const char*)As + row * 128 + c * 16);
      }
      #pragma unroll
      for (int n = 0; n < 4; ++n) {
        int row = wn * 64 + n * 16 + (l & 15);
        int c   = (kk * 4 + (l >> 4)) ^ (row & 7);
        bfr[n] = *(const bf16x8*)((const char*)Bs + row * 128 + c * 16);
      }
      #pragma unroll
      for (int m = 0; m < 4; ++m)
        #pragma unroll
        for (int n = 0; n < 4; ++n)
          acc[m][n] = __builtin_amdgcn_mfma_f32_16x16x32_bf16(af[m], bfr[n], acc[m][n], 0, 0, 0);
    }
  }

  // epilogue: C/D layout col = l&15, row = (l>>4)*4 + reg
  #pragma unroll
  for (int m = 0; m < 4; ++m) {
    #pragma unroll
    for (int n = 0; n < 4; ++n) {
      #pragma unroll
      for (int j = 0; j < 4; ++j) {
        int rloc = wm * 64 + m * 16 + ((l >> 4) * 4 + j);
        int cloc = wn * 64 + n * 16 + (l & 15);
        int r  = tm * 128 + rloc;
        int cg = tn * 128 + cloc;
        float v = acc[m][n][j];
        if (MODE == 0) {
          C[(size_t)r * ldc + cg] = v + bias[cg];
        } else {
          if (cg < V_) {
            int t = r >> 7, b = r & 127;
            C[(size_t)b * SV + (size_t)t * V_ + cg] = v + bias[cg];
          }
        }
      }
    }
  }
}

// ---------------------------------------------------------------------------
// Persistent recurrence: 16 WGs x 4 waves; wave owns a 32x32 tile of [128][512].
// state_{t+1} = tanh(pre[t] + state_t @ Wc_h), Wc_h = Wct[:, 1024:1536].
// Grid sync via device-scope atomic counter (16 WGs always co-resident).
// ---------------------------------------------------------------------------
__global__ __launch_bounds__(256) void rnn_steps(
    __hip_bfloat16* __restrict__ sbf,       // [26][128][512] bf16, [0]=init
    const float* __restrict__ pre,          // [3200][512] f32
    const __hip_bfloat16* __restrict__ wct, // [512][1536] k-major
    float* __restrict__ fstate,             // d_out + 32M (final state f32)
    unsigned* __restrict__ cnt)
{
  const int g = blockIdx.x, tid = threadIdx.x;
  const int w = tid >> 6, l = tid & 63;
  const int rows0 = (g >> 2) * 32;
  const int cols0 = (g & 3) * 128 + w * 32;

  for (int t = 0; t < 25; ++t) {
    const __hip_bfloat16* Acur = sbf + (size_t)t * 65536;
    f32x4 acc[2][2];
    #pragma unroll
    for (int m2 = 0; m2 < 2; ++m2)
      #pragma unroll
      for (int n2 = 0; n2 < 2; ++n2)
        #pragma unroll
        for (int j = 0; j < 4; ++j) {
          int row = rows0 + m2 * 16 + ((l >> 4) * 4 + j);
          int col = cols0 + n2 * 16 + (l & 15);
          acc[m2][n2][j] = pre[((size_t)t * 128 + row) * 512 + col];
        }
    #pragma unroll 4
    for (int kk = 0; kk < 16; ++kk) {
      int k = kk * 32 + (l >> 4) * 8;
      bf16x8 a[2], b[2];
      #pragma unroll
      for (int m2 = 0; m2 < 2; ++m2)
        a[m2] = *(const bf16x8*)(Acur + (size_t)(rows0 + m2 * 16 + (l & 15)) * 512 + k);
      #pragma unroll
      for (int n2 = 0; n2 < 2; ++n2)
        b[n2] = *(const bf16x8*)(wct + (size_t)(cols0 + n2 * 16 + (l & 15)) * 1536 + 1024 + k);
      #pragma unroll
      for (int m2 = 0; m2 < 2; ++m2)
        #pragma unroll
        for (int n2 = 0; n2 < 2; ++n2)
          acc[m2][n2] = __builtin_amdgcn_mfma_f32_16x16x32_bf16(a[m2], b[n2], acc[m2][n2], 0, 0, 0);
    }
    __hip_bfloat16* Sn = sbf + (size_t)(t + 1) * 65536;
    #pragma unroll
    for (int m2 = 0; m2 < 2; ++m2)
      #pragma unroll
      for (int n2 = 0; n2 < 2; ++n2)
        #pragma unroll
        for (int j = 0; j < 4; ++j) {
          int row = rows0 + m2 * 16 + ((l >> 4) * 4 + j);
          int col = cols0 + n2 * 16 + (l & 15);
          float v = tanhf(acc[m2][n2][j]);
          Sn[(size_t)row * 512 + col] = __float2bfloat16(v);
          if (t == 24) fstate[(size_t)row * 512 + col] = v;
        }
    // grid-wide sync (release data, wait for all 16 WGs)
    __syncthreads();
    if (tid == 0) {
      __hip_atomic_fetch_add(cnt, 1u, __ATOMIC_ACQ_REL, __HIP_MEMORY_SCOPE_AGENT);
      unsigned target = 16u * (unsigned)(t + 1);
      while (__hip_atomic_load(cnt, __ATOMIC_ACQUIRE, __HIP_MEMORY_SCOPE_AGENT) < target)
        __builtin_amdgcn_s_sleep(2);
    }
    __syncthreads();
  }
}

// ---------------------------------------------------------------------------
extern "C" void kernel_launch(void* const* d_in, const int* in_sizes, int n_in,
                              void* d_out, int out_size, void* d_ws, size_t ws_size,
                              hipStream_t stream) {
  const int*   xT   = (const int*)d_in[0];
  const float* base = (const float*)d_in[1];
  const float* init = (const float*)d_in[2];
  const float* emb  = (const float*)d_in[3];
  const float* Wc   = (const float*)d_in[4];
  const float* bc   = (const float*)d_in[5];
  const float* Wo   = (const float*)d_in[6];
  const float* bo   = (const float*)d_in[7];
  float* out = (float*)d_out;

  char* ws = (char*)d_ws;
  // ws layout (all 1KB-aligned):
  __hip_bfloat16* WCT = (__hip_bfloat16*)(ws + 0);          // [512][1536]  1.57 MB
  __hip_bfloat16* WOT = (__hip_bfloat16*)(ws + 1572864);    // [10112][512] 10.35 MB
  unsigned short* A1  = (unsigned short*)(ws + 11927552);   // [3200][1024] 6.55 MB
  float*          PRE = (float*)(ws + 18481152);            // [3200][512]  6.55 MB
  __hip_bfloat16* SBF = (__hip_bfloat16*)(ws + 25034752);   // [26][128][512] 3.41 MB
  unsigned*       CNT = (unsigned*)(ws + 28442624);

  // 1) weights -> k-major bf16 (Wout padded to 10112 rows, zero-filled)
  transpose_to_bf16<<<dim3(16, 48), 256, 0, stream>>>(Wc, WCT, KCAT, 512, 512);
  transpose_to_bf16<<<dim3(316, 16), 256, 0, stream>>>(Wo, WOT, 512, V_, NPAD);
  // 2) gather [base; emb] rows, init state, zero sync counter
  build_a1<<<3200, 256, 0, stream>>>(xT, base, init, emb, A1, SBF, CNT);
  // 3) pre[t,b,:] = [base;emb] @ Wc[0:1024] + b_cell   (M=3200,N=512,K=1024)
  gemm_bt<0><<<dim3(4, 25), 256, 0, stream>>>(
      (const __hip_bfloat16*)A1, WCT, bc, PRE, 1024, 1024, KCAT, 512);
  // 4) sequential recurrence (25 steps, persistent kernel)
  rnn_steps<<<16, 256, 0, stream>>>(SBF, PRE, WCT, out + 32000000, CNT);
  // 5) logits = states @ Wout + b_out  (M=3200,N=10112->10000,K=512)
  gemm_bt<1><<<dim3(79, 25), 256, 0, stream>>>(
      SBF + 65536, WOT, bo, out, 512, 512, 512, 0);
}

// Round 5
// 619.452 us; speedup vs baseline: 1.0547x; 1.0547x over previous
//
#include <hip/hip_runtime.h>
#include <hip/hip_bf16.h>

// Problem dims (fixed)
#define B_   128
#define S_   25
#define E_   512
#define F_   512
#define H_   512
#define V_   10000
#define KCAT 1536        // F+E+H
#define M_   3200        // B*S
#define NPAD 10112       // 79*128 (padded V)
#define SV   250000      // S*V

typedef __attribute__((ext_vector_type(8))) short bf16x8;   // 8 bf16 in 4 VGPRs
typedef __attribute__((ext_vector_type(4))) float f32x4;

__device__ inline unsigned short f2bf(float f) {
  __hip_bfloat16 h = __float2bfloat16(f);
  return *reinterpret_cast<unsigned short*>(&h);
}

// ---------------------------------------------------------------------------
// Transpose-convert: in f32 [K][N] row-major  ->  out bf16 [Npad][K] (k-major)
// Rows n >= N are zero-filled (padding for the GEMM N-tiles).
// ---------------------------------------------------------------------------
__global__ __launch_bounds__(256) void transpose_to_bf16(
    const float* __restrict__ in, __hip_bfloat16* __restrict__ out,
    int K, int N, int Npad)
{
  __shared__ float tile[32][33];
  int n0 = blockIdx.x * 32, k0 = blockIdx.y * 32;
  int tx = threadIdx.x & 31, ty = threadIdx.x >> 5;   // 32 x 8
  #pragma unroll
  for (int i = 0; i < 32; i += 8) {
    int k = k0 + ty + i, n = n0 + tx;
    tile[ty + i][tx] = (n < N) ? in[(size_t)k * N + n] : 0.0f;
  }
  __syncthreads();
  #pragma unroll
  for (int i = 0; i < 32; i += 8) {
    int n = n0 + ty + i, k = k0 + tx;
    out[(size_t)n * K + k] = __float2bfloat16(tile[tx][ty + i]);
  }
}

// ---------------------------------------------------------------------------
// Build A1[r=t*128+b][0:512]=bf16(base[b]), [512:1024]=bf16(emb[tok(b,t)]).
// ---------------------------------------------------------------------------
__global__ __launch_bounds__(256) void build_a1(
    const int* __restrict__ xT, const float* __restrict__ base,
    const float* __restrict__ emb, unsigned short* __restrict__ A1)
{
  int r = blockIdx.x; int t = r >> 7, b = r & 127;
  int tid = threadIdx.x;
  int tok = xT[b * S_ + t];
  const float* src = (tid < 128) ? (base + (size_t)b * 512 + tid * 4)
                                 : (emb + (size_t)tok * 512 + (tid - 128) * 4);
  float4 v = *(const float4*)src;
  ushort4 o;
  o.x = f2bf(v.x); o.y = f2bf(v.y); o.z = f2bf(v.z); o.w = f2bf(v.w);
  *(ushort4*)(A1 + (size_t)r * 1024 + tid * 4) = o;
}

// ---------------------------------------------------------------------------
// GEMM  C = A[M][lda] @ Bt[N][ldb]^T + bias  (both operands bf16 k-major)
// 128x128 tile, BK=64, 4 waves (2x2), each wave 64x64 via 4x4 16x16x32 MFMA.
// Staging: direct global->LDS (global_load_lds dwordx4), linear LDS dest,
// PRE-SWIZZLED global source chunk cs = (l&7) ^ (l>>3), so LDS position
// c_pos holds global chunk c_pos ^ (row&7)  (same layout as validated r1).
// MODE 0: C[r*ldc + n] = v + bias[n]          (pre-activation buffer)
// MODE 1: logits scatter C[b*SV + t*V + n] (n < V only), r = t*128+b
// ---------------------------------------------------------------------------
template<int MODE>
__global__ __launch_bounds__(256) void gemm_bt(
    const __hip_bfloat16* __restrict__ A,
    const __hip_bfloat16* __restrict__ Bt,
    const float* __restrict__ bias,
    float* __restrict__ C,
    int K, int lda, int ldb, int ldc)
{
  __shared__ short As[128 * 64];
  __shared__ short Bs[128 * 64];
  const int tid = threadIdx.x;
  const int w = tid >> 6, l = tid & 63;
  const int tm = blockIdx.y, tn = blockIdx.x;
  const int wm = w >> 1, wn = w & 1;

  f32x4 acc[4][4] = {};

  const int lr = l >> 3;           // local row within 8-row block (== row&7)
  const int cs = (l & 7) ^ lr;     // pre-swizzled global 16B-chunk index

  const int nKT = K >> 6;
  for (int kt = 0; kt < nKT; ++kt) {
    const int k0 = kt << 6;
    __syncthreads();   // previous iteration's MFMA reads of LDS are done
    #pragma unroll
    for (int p = 0; p < 4; ++p) {
      int rowblk = p * 32 + w * 8;         // wave-uniform 8-row block
      int row = rowblk + lr;
      const char* ga = (const char*)(A  + (size_t)(tm * 128 + row) * lda + k0) + cs * 16;
      const char* gb = (const char*)(Bt + (size_t)(tn * 128 + row) * ldb + k0) + cs * 16;
      char* la = (char*)As + rowblk * 128; // wave-uniform LDS base; HW adds lane*16
      char* lb = (char*)Bs + rowblk * 128;
      __builtin_amdgcn_global_load_lds(
          (const __attribute__((address_space(1))) unsigned*)ga,
          (__attribute__((address_space(3))) unsigned*)la, 16, 0, 0);
      __builtin_amdgcn_global_load_lds(
          (const __attribute__((address_space(1))) unsigned*)gb,
          (__attribute__((address_space(3))) unsigned*)lb, 16, 0, 0);
    }
    __syncthreads();   // vmcnt(0) drained by compiler before barrier
    #pragma unroll
    for (int kk = 0; kk < 2; ++kk) {
      bf16x8 af[4], bfr[4];
      #pragma unroll
      for (int m = 0; m < 4; ++m) {
        int row = wm * 64 + m * 16 + (l & 15);
        int c   = (kk * 4 + (l >> 4)) ^ (row & 7);
        af[m] = *(const bf16x8*)((const char*)As + row * 128 + c * 16);
      }
      #pragma unroll
      for (int n = 0; n < 4; ++n) {
        int row = wn * 64 + n * 16 + (l & 15);
        int c   = (kk * 4 + (l >> 4)) ^ (row & 7);
        bfr[n] = *(const bf16x8*)((const char*)Bs + row * 128 + c * 16);
      }
      #pragma unroll
      for (int m = 0; m < 4; ++m)
        #pragma unroll
        for (int n = 0; n < 4; ++n)
          acc[m][n] = __builtin_amdgcn_mfma_f32_16x16x32_bf16(af[m], bfr[n], acc[m][n], 0, 0, 0);
    }
  }

  // epilogue: C/D layout col = l&15, row = (l>>4)*4 + reg
  #pragma unroll
  for (int m = 0; m < 4; ++m) {
    #pragma unroll
    for (int n = 0; n < 4; ++n) {
      #pragma unroll
      for (int j = 0; j < 4; ++j) {
        int rloc = wm * 64 + m * 16 + ((l >> 4) * 4 + j);
        int cloc = wn * 64 + n * 16 + (l & 15);
        int r  = tm * 128 + rloc;
        int cg = tn * 128 + cloc;
        float v = acc[m][n][j];
        if (MODE == 0) {
          C[(size_t)r * ldc + cg] = v + bias[cg];
        } else {
          if (cg < V_) {
            int t = r >> 7, b = r & 127;
            C[(size_t)b * SV + (size_t)t * V_ + cg] = v + bias[cg];
          }
        }
      }
    }
  }
}

// ---------------------------------------------------------------------------
// Recurrence v2: batch-parallel, ZERO grid syncs.
// 8 WGs x 1024 threads (16 waves). WG g owns batch rows [16g, 16g+16).
// State tile [16][512] bf16 lives in LDS (ping-pong, XOR-chunk swizzle).
// Wave w computes output cols [32w, 32w+32) each step; weights streamed
// from (XCD-local, L2-resident) wct.  state_{t+1} = tanh(pre[t] + s_t @ Wc_h).
// ---------------------------------------------------------------------------
__global__ __launch_bounds__(1024) void rnn_steps(
    const float* __restrict__ init,         // [128][512] f32
    __hip_bfloat16* __restrict__ sbf,       // [26][128][512] bf16 (slot 0 unused)
    const float* __restrict__ pre,          // [3200][512] f32
    const __hip_bfloat16* __restrict__ wct, // [512][1536] k-major
    float* __restrict__ fstate)             // d_out + 32M (final state f32)
{
  __shared__ short st[2][16 * 512];
  const int g = blockIdx.x;
  const int r0 = g * 16;
  const int tid = threadIdx.x;
  const int w = tid >> 6, l = tid & 63;
  const int c0 = w * 32;                    // this wave's 32 output cols

  // load init state rows -> LDS buf 0 (16B chunk c stored at c ^ (row&7))
  {
    int row = tid >> 6;                     // 0..15
    int c   = tid & 63;                     // 64 chunks of 8 bf16 per row
    const float* s = init + (size_t)(r0 + row) * 512 + c * 8;
    float4 v0 = *(const float4*)s;
    float4 v1 = *(const float4*)(s + 4);
    alignas(16) unsigned short u[8] = {f2bf(v0.x), f2bf(v0.y), f2bf(v0.z), f2bf(v0.w),
                                       f2bf(v1.x), f2bf(v1.y), f2bf(v1.z), f2bf(v1.w)};
    *(uint4*)((char*)st[0] + row * 1024 + (c ^ (row & 7)) * 16) = *(const uint4*)u;
  }
  __syncthreads();

  int p = 0;
  for (int t = 0; t < 25; ++t) {
    f32x4 acc[2];
    const float* prow = pre + ((size_t)t * 128 + r0) * 512;
    #pragma unroll
    for (int n2 = 0; n2 < 2; ++n2)
      #pragma unroll
      for (int j = 0; j < 4; ++j)
        acc[n2][j] = prow[(size_t)((l >> 4) * 4 + j) * 512 + c0 + n2 * 16 + (l & 15)];

    #pragma unroll 4
    for (int kk = 0; kk < 16; ++kk) {
      int k8  = kk * 32 + (l >> 4) * 8;
      int row = l & 15;
      bf16x8 a = *(const bf16x8*)((const char*)st[p] + row * 1024 +
                                  (((k8 >> 3) ^ (row & 7)) * 16));
      bf16x8 b0 = *(const bf16x8*)(wct + (size_t)(c0 + (l & 15)) * 1536 + 1024 + k8);
      bf16x8 b1 = *(const bf16x8*)(wct + (size_t)(c0 + 16 + (l & 15)) * 1536 + 1024 + k8);
      acc[0] = __builtin_amdgcn_mfma_f32_16x16x32_bf16(a, b0, acc[0], 0, 0, 0);
      acc[1] = __builtin_amdgcn_mfma_f32_16x16x32_bf16(a, b1, acc[1], 0, 0, 0);
    }

    // activation + write to SBF (for logits GEMM) and LDS ping-pong buffer
    __hip_bfloat16* Sn = sbf + (size_t)(t + 1) * 65536 + (size_t)r0 * 512;
    #pragma unroll
    for (int n2 = 0; n2 < 2; ++n2)
      #pragma unroll
      for (int j = 0; j < 4; ++j) {
        int row = (l >> 4) * 4 + j;
        int col = c0 + n2 * 16 + (l & 15);
        float x = acc[n2][j];
        float e = __expf(2.0f * x);
        float v = 1.0f - 2.0f / (e + 1.0f);     // tanh(x), fast path
        Sn[(size_t)row * 512 + col] = __float2bfloat16(v);
        *(short*)((char*)st[p ^ 1] + row * 1024 +
                  ((col >> 3) ^ (row & 7)) * 16 + (col & 7) * 2) = (short)f2bf(v);
        if (t == 24) fstate[(size_t)(r0 + row) * 512 + col] = v;
      }
    __syncthreads();   // writes to st[p^1] visible; reads of st[p] done
    p ^= 1;
  }
}

// ---------------------------------------------------------------------------
extern "C" void kernel_launch(void* const* d_in, const int* in_sizes, int n_in,
                              void* d_out, int out_size, void* d_ws, size_t ws_size,
                              hipStream_t stream) {
  const int*   xT   = (const int*)d_in[0];
  const float* base = (const float*)d_in[1];
  const float* init = (const float*)d_in[2];
  const float* emb  = (const float*)d_in[3];
  const float* Wc   = (const float*)d_in[4];
  const float* bc   = (const float*)d_in[5];
  const float* Wo   = (const float*)d_in[6];
  const float* bo   = (const float*)d_in[7];
  float* out = (float*)d_out;

  char* ws = (char*)d_ws;
  // ws layout (all 1KB-aligned):
  __hip_bfloat16* WCT = (__hip_bfloat16*)(ws + 0);          // [512][1536]  1.57 MB
  __hip_bfloat16* WOT = (__hip_bfloat16*)(ws + 1572864);    // [10112][512] 10.35 MB
  unsigned short* A1  = (unsigned short*)(ws + 11927552);   // [3200][1024] 6.55 MB
  float*          PRE = (float*)(ws + 18481152);            // [3200][512]  6.55 MB
  __hip_bfloat16* SBF = (__hip_bfloat16*)(ws + 25034752);   // [26][128][512] 3.41 MB

  // 1) weights -> k-major bf16 (Wout padded to 10112 rows, zero-filled)
  transpose_to_bf16<<<dim3(16, 48), 256, 0, stream>>>(Wc, WCT, KCAT, 512, 512);
  transpose_to_bf16<<<dim3(316, 16), 256, 0, stream>>>(Wo, WOT, 512, V_, NPAD);
  // 2) gather [base; emb] rows
  build_a1<<<3200, 256, 0, stream>>>(xT, base, emb, A1);
  // 3) pre[t,b,:] = [base;emb] @ Wc[0:1024] + b_cell   (M=3200,N=512,K=1024)
  gemm_bt<0><<<dim3(4, 25), 256, 0, stream>>>(
      (const __hip_bfloat16*)A1, WCT, bc, PRE, 1024, 1024, KCAT, 512);
  // 4) sequential recurrence (25 steps, batch-parallel, no grid sync)
  rnn_steps<<<8, 1024, 0, stream>>>(init, SBF, PRE, WCT, out + 32000000);
  // 5) logits = states @ Wout + b_out  (M=3200,N=10112->10000,K=512)
  gemm_bt<1><<<dim3(79, 25), 256, 0, stream>>>(
      SBF + 65536, WOT, bo, out, 512, 512, 512, 0);
}

// Round 7
// 471.520 us; speedup vs baseline: 1.3856x; 1.3137x over previous
//
#include <hip/hip_runtime.h>
#include <hip/hip_bf16.h>

// Problem dims (fixed)
#define B_   128
#define S_   25
#define E_   512
#define F_   512
#define H_   512
#define V_   10000
#define KCAT 1536        // F+E+H
#define M_   3200        // B*S
#define NPAD 10112       // 79*128 (padded V)
#define SV   250000      // S*V

typedef __attribute__((ext_vector_type(8))) short bf16x8;   // 8 bf16 in 4 VGPRs
typedef __attribute__((ext_vector_type(4))) float f32x4;

__device__ inline unsigned short f2bf(float f) {
  __hip_bfloat16 h = __float2bfloat16(f);
  return *reinterpret_cast<unsigned short*>(&h);
}

// ---------------------------------------------------------------------------
// Transpose-convert: in f32 [K][N] row-major  ->  out bf16 [Npad][K] (k-major)
// Rows n >= N are zero-filled (padding for the GEMM N-tiles).
// ---------------------------------------------------------------------------
__global__ __launch_bounds__(256) void transpose_to_bf16(
    const float* __restrict__ in, __hip_bfloat16* __restrict__ out,
    int K, int N, int Npad)
{
  __shared__ float tile[32][33];
  int n0 = blockIdx.x * 32, k0 = blockIdx.y * 32;
  int tx = threadIdx.x & 31, ty = threadIdx.x >> 5;   // 32 x 8
  #pragma unroll
  for (int i = 0; i < 32; i += 8) {
    int k = k0 + ty + i, n = n0 + tx;
    tile[ty + i][tx] = (n < N) ? in[(size_t)k * N + n] : 0.0f;
  }
  __syncthreads();
  #pragma unroll
  for (int i = 0; i < 32; i += 8) {
    int n = n0 + ty + i, k = k0 + tx;
    out[(size_t)n * K + k] = __float2bfloat16(tile[tx][ty + i]);
  }
}

// ---------------------------------------------------------------------------
// Build A1[r=t*128+b][0:512]=bf16(base[b]), [512:1024]=bf16(emb[tok(b,t)]).
// ---------------------------------------------------------------------------
__global__ __launch_bounds__(256) void build_a1(
    const int* __restrict__ xT, const float* __restrict__ base,
    const float* __restrict__ emb, unsigned short* __restrict__ A1)
{
  int r = blockIdx.x; int t = r >> 7, b = r & 127;
  int tid = threadIdx.x;
  int tok = xT[b * S_ + t];
  const float* src = (tid < 128) ? (base + (size_t)b * 512 + tid * 4)
                                 : (emb + (size_t)tok * 512 + (tid - 128) * 4);
  float4 v = *(const float4*)src;
  ushort4 o;
  o.x = f2bf(v.x); o.y = f2bf(v.y); o.z = f2bf(v.z); o.w = f2bf(v.w);
  *(ushort4*)(A1 + (size_t)r * 1024 + tid * 4) = o;
}

// ---------------------------------------------------------------------------
// GEMM  C = A[M][lda] @ Bt[N][ldb]^T + bias  (both operands bf16 k-major)
// 128x128 tile, BK=64, 4 waves (2x2), each wave 64x64 via 4x4 16x16x32 MFMA.
// Staging: direct global->LDS (global_load_lds dwordx4), linear LDS dest,
// PRE-SWIZZLED global source chunk cs = (l&7) ^ (l>>3), so LDS position
// c_pos holds global chunk c_pos ^ (row&7)  (same layout as validated r1).
// MODE 0: C[r*ldc + n] = v + bias[n]          (pre-activation buffer)
// MODE 1: logits scatter C[b*SV + t*V + n] (n < V only), r = t*128+b
// ---------------------------------------------------------------------------
template<int MODE>
__global__ __launch_bounds__(256) void gemm_bt(
    const __hip_bfloat16* __restrict__ A,
    const __hip_bfloat16* __restrict__ Bt,
    const float* __restrict__ bias,
    float* __restrict__ C,
    int K, int lda, int ldb, int ldc)
{
  __shared__ short As[128 * 64];
  __shared__ short Bs[128 * 64];
  const int tid = threadIdx.x;
  const int w = tid >> 6, l = tid & 63;
  const int tm = blockIdx.y, tn = blockIdx.x;
  const int wm = w >> 1, wn = w & 1;

  f32x4 acc[4][4] = {};

  const int lr = l >> 3;           // local row within 8-row block (== row&7)
  const int cs = (l & 7) ^ lr;     // pre-swizzled global 16B-chunk index

  const int nKT = K >> 6;
  for (int kt = 0; kt < nKT; ++kt) {
    const int k0 = kt << 6;
    __syncthreads();   // previous iteration's MFMA reads of LDS are done
    #pragma unroll
    for (int p = 0; p < 4; ++p) {
      int rowblk = p * 32 + w * 8;         // wave-uniform 8-row block
      int row = rowblk + lr;
      const char* ga = (const char*)(A  + (size_t)(tm * 128 + row) * lda + k0) + cs * 16;
      const char* gb = (const char*)(Bt + (size_t)(tn * 128 + row) * ldb + k0) + cs * 16;
      char* la = (char*)As + rowblk * 128; // wave-uniform LDS base; HW adds lane*16
      char* lb = (char*)Bs + rowblk * 128;
      __builtin_amdgcn_global_load_lds(
          (const __attribute__((address_space(1))) unsigned*)ga,
          (__attribute__((address_space(3))) unsigned*)la, 16, 0, 0);
      __builtin_amdgcn_global_load_lds(
          (const __attribute__((address_space(1))) unsigned*)gb,
          (__attribute__((address_space(3))) unsigned*)lb, 16, 0, 0);
    }
    __syncthreads();   // vmcnt(0) drained by compiler before barrier
    #pragma unroll
    for (int kk = 0; kk < 2; ++kk) {
      bf16x8 af[4], bfr[4];
      #pragma unroll
      for (int m = 0; m < 4; ++m) {
        int row = wm * 64 + m * 16 + (l & 15);
        int c   = (kk * 4 + (l >> 4)) ^ (row & 7);
        af[m] = *(const bf16x8*)((const char*)As + row * 128 + c * 16);
      }
      #pragma unroll
      for (int n = 0; n < 4; ++n) {
        int row = wn * 64 + n * 16 + (l & 15);
        int c   = (kk * 4 + (l >> 4)) ^ (row & 7);
        bfr[n] = *(const bf16x8*)((const char*)Bs + row * 128 + c * 16);
      }
      #pragma unroll
      for (int m = 0; m < 4; ++m)
        #pragma unroll
        for (int n = 0; n < 4; ++n)
          acc[m][n] = __builtin_amdgcn_mfma_f32_16x16x32_bf16(af[m], bfr[n], acc[m][n], 0, 0, 0);
    }
  }

  // epilogue: C/D layout col = l&15, row = (l>>4)*4 + reg
  #pragma unroll
  for (int m = 0; m < 4; ++m) {
    #pragma unroll
    for (int n = 0; n < 4; ++n) {
      #pragma unroll
      for (int j = 0; j < 4; ++j) {
        int rloc = wm * 64 + m * 16 + ((l >> 4) * 4 + j);
        int cloc = wn * 64 + n * 16 + (l & 15);
        int r  = tm * 128 + rloc;
        int cg = tn * 128 + cloc;
        float v = acc[m][n][j];
        if (MODE == 0) {
          C[(size_t)r * ldc + cg] = v + bias[cg];
        } else {
          if (cg < V_) {
            int t = r >> 7, b = r & 127;
            C[(size_t)b * SV + (size_t)t * V_ + cg] = v + bias[cg];
          }
        }
      }
    }
  }
}

// ---------------------------------------------------------------------------
// Recurrence v3: batch-parallel + REGISTER-RESIDENT weights.
// 8 WGs x 512 threads (8 waves, 2 waves/SIMD, 256-VGPR cap).
// WG g owns batch rows [16g,16g+16); wave w owns output cols [64w,64w+64).
// Wc_h slice per wave: kk=0..9 (k<320) held in 40 loop-invariant B-fragments
// (160 VGPR); kk=10..15 streamed from L2 each step (192 KB/CU/step).
// State [16][512] bf16 in LDS ping-pong (XOR chunk swizzle, 1 barrier/step).
// PRE loaded early into regs, added AFTER the MFMA chain (latency hidden).
// ---------------------------------------------------------------------------
__global__ __launch_bounds__(512, 2) void rnn_steps(
    const float* __restrict__ init,         // [128][512] f32
    __hip_bfloat16* __restrict__ sbf,       // [26][128][512] bf16 (slot 0 unused)
    const float* __restrict__ pre,          // [3200][512] f32
    const __hip_bfloat16* __restrict__ wct, // [512][1536] k-major
    float* __restrict__ fstate)             // d_out + 32M (final state f32)
{
  __shared__ short st[2][16 * 512];
  const int g = blockIdx.x;
  const int r0 = g * 16;
  const int tid = threadIdx.x;
  const int w = tid >> 6, l = tid & 63;
  const int c0 = w * 64;                    // wave's 64 output cols (4 blocks)

  // frag(cb,kk): lane l holds W[k=kk*32+(l>>4)*8+j][col=c0+cb*16+(l&15)]
  const __hip_bfloat16* wbase =
      wct + (size_t)(c0 + (l & 15)) * 1536 + 1024 + (l >> 4) * 8;

  // ---- resident weight fragments kk=0..9 (loaded once, live 25 steps)
  bf16x8 fr[4][10];
  #pragma unroll
  for (int cb = 0; cb < 4; ++cb)
    #pragma unroll
    for (int kk = 0; kk < 10; ++kk)
      fr[cb][kk] = *(const bf16x8*)(wbase + (size_t)cb * 16 * 1536 + kk * 32);

  // ---- init state rows -> LDS buf 0 (16B chunk c stored at c ^ (row&7))
  {
    int row = tid >> 5;                     // 0..15
    int c2  = (tid & 31) * 2;               // two chunks per thread
    const float* s = init + (size_t)(r0 + row) * 512 + c2 * 8;
    #pragma unroll
    for (int q = 0; q < 2; ++q) {
      int c = c2 + q;
      float4 v0 = *(const float4*)(s + q * 8);
      float4 v1 = *(const float4*)(s + q * 8 + 4);
      alignas(16) unsigned short u[8] = {f2bf(v0.x), f2bf(v0.y), f2bf(v0.z), f2bf(v0.w),
                                         f2bf(v1.x), f2bf(v1.y), f2bf(v1.z), f2bf(v1.w)};
      *(uint4*)((char*)st[0] + row * 1024 + (c ^ (row & 7)) * 16) = *(const uint4*)u;
    }
  }
  __syncthreads();

  int p = 0;
  #pragma unroll 1
  for (int t = 0; t < 25; ++t) {
    // early PRE loads (consumed only at the end of the step)
    float pv[4][4];
    const float* prow = pre + ((size_t)t * 128 + r0) * 512;
    #pragma unroll
    for (int cb = 0; cb < 4; ++cb)
      #pragma unroll
      for (int j = 0; j < 4; ++j)
        pv[cb][j] = prow[(size_t)((l >> 4) * 4 + j) * 512 + c0 + cb * 16 + (l & 15)];

    f32x4 acc[4] = {};

    // resident-K portion: kk = 0..9
    #pragma unroll
    for (int kk = 0; kk < 10; ++kk) {
      bf16x8 a = *(const bf16x8*)((const char*)st[p] + (l & 15) * 1024 +
                                  (((kk * 4 + (l >> 4)) ^ (l & 7)) * 16));
      #pragma unroll
      for (int cb = 0; cb < 4; ++cb)
        acc[cb] = __builtin_amdgcn_mfma_f32_16x16x32_bf16(a, fr[cb][kk], acc[cb], 0, 0, 0);
    }
    // streamed-K portion: kk = 10..15 (L2-resident, loads front-scheduled)
    #pragma unroll
    for (int kk = 10; kk < 16; ++kk) {
      bf16x8 a = *(const bf16x8*)((const char*)st[p] + (l & 15) * 1024 +
                                  (((kk * 4 + (l >> 4)) ^ (l & 7)) * 16));
      #pragma unroll
      for (int cb = 0; cb < 4; ++cb) {
        bf16x8 b = *(const bf16x8*)(wbase + (size_t)cb * 16 * 1536 + kk * 32);
        acc[cb] = __builtin_amdgcn_mfma_f32_16x16x32_bf16(a, b, acc[cb], 0, 0, 0);
      }
    }

    // add PRE, activation, write SBF + LDS ping-pong (+ final state at t=24)
    __hip_bfloat16* Sn = sbf + (size_t)(t + 1) * 65536 + (size_t)r0 * 512;
    #pragma unroll
    for (int cb = 0; cb < 4; ++cb)
      #pragma unroll
      for (int j = 0; j < 4; ++j) {
        int row = (l >> 4) * 4 + j;
        int col = c0 + cb * 16 + (l & 15);
        float x = acc[cb][j] + pv[cb][j];
        float e = __expf(2.0f * x);
        float v = 1.0f - 2.0f / (e + 1.0f);     // tanh(x), fast path
        Sn[(size_t)row * 512 + col] = __float2bfloat16(v);
        *(short*)((char*)st[p ^ 1] + row * 1024 +
                  ((col >> 3) ^ (row & 7)) * 16 + (col & 7) * 2) = (short)f2bf(v);
        if (t == 24) fstate[(size_t)(r0 + row) * 512 + col] = v;
      }
    __syncthreads();   // writes to st[p^1] visible; reads of st[p] done
    p ^= 1;
  }
}

// ---------------------------------------------------------------------------
extern "C" void kernel_launch(void* const* d_in, const int* in_sizes, int n_in,
                              void* d_out, int out_size, void* d_ws, size_t ws_size,
                              hipStream_t stream) {
  const int*   xT   = (const int*)d_in[0];
  const float* base = (const float*)d_in[1];
  const float* init = (const float*)d_in[2];
  const float* emb  = (const float*)d_in[3];
  const float* Wc   = (const float*)d_in[4];
  const float* bc   = (const float*)d_in[5];
  const float* Wo   = (const float*)d_in[6];
  const float* bo   = (const float*)d_in[7];
  float* out = (float*)d_out;

  char* ws = (char*)d_ws;
  // ws layout (all 1KB-aligned):
  __hip_bfloat16* WCT = (__hip_bfloat16*)(ws + 0);          // [512][1536]  1.57 MB
  __hip_bfloat16* WOT = (__hip_bfloat16*)(ws + 1572864);    // [10112][512] 10.35 MB
  unsigned short* A1  = (unsigned short*)(ws + 11927552);   // [3200][1024] 6.55 MB
  float*          PRE = (float*)(ws + 18481152);            // [3200][512]  6.55 MB
  __hip_bfloat16* SBF = (__hip_bfloat16*)(ws + 25034752);   // [26][128][512] 3.41 MB

  // 1) weights -> k-major bf16 (Wout padded to 10112 rows, zero-filled)
  transpose_to_bf16<<<dim3(16, 48), 256, 0, stream>>>(Wc, WCT, KCAT, 512, 512);
  transpose_to_bf16<<<dim3(316, 16), 256, 0, stream>>>(Wo, WOT, 512, V_, NPAD);
  // 2) gather [base; emb] rows
  build_a1<<<3200, 256, 0, stream>>>(xT, base, emb, A1);
  // 3) pre[t,b,:] = [base;emb] @ Wc[0:1024] + b_cell   (M=3200,N=512,K=1024)
  gemm_bt<0><<<dim3(4, 25), 256, 0, stream>>>(
      (const __hip_bfloat16*)A1, WCT, bc, PRE, 1024, 1024, KCAT, 512);
  // 4) sequential recurrence (25 steps, register-resident weights)
  rnn_steps<<<8, 512, 0, stream>>>(init, SBF, PRE, WCT, out + 32000000);
  // 5) logits = states @ Wout + b_out  (M=3200,N=10112->10000,K=512)
  gemm_bt<1><<<dim3(79, 25), 256, 0, stream>>>(
      SBF + 65536, WOT, bo, out, 512, 512, 512, 0);
}